// Round 5
// baseline (751.737 us; speedup 1.0000x reference)
//
#include <hip/hip_runtime.h>

#define NN 20000      // nodes
#define NE 320000     // edges
#define SS 2          // feature axis
#define FIN 128
#define FH 246

// ---------------- degree histogram ----------------
__global__ void degree_kernel(const int* __restrict__ src, const int* __restrict__ dst,
                              int* __restrict__ deg_out, int* __restrict__ deg_in) {
    int e = blockIdx.x * blockDim.x + threadIdx.x;
    if (e < NE) {
        atomicAdd(&deg_out[src[e]], 1);
        atomicAdd(&deg_in[dst[e]], 1);
    }
}

// ---------------- norms ----------------
__global__ void norm_kernel(const int* __restrict__ deg_out, const int* __restrict__ deg_in,
                            float* __restrict__ norm_out, float* __restrict__ norm_in) {
    int n = blockIdx.x * blockDim.x + threadIdx.x;
    if (n < NN) {
        norm_out[n] = rsqrtf(fmaxf((float)deg_out[n], 1.0f));
        norm_in[n]  = rsqrtf(fmaxf((float)deg_in[n], 1.0f));
    }
}

// ---------------- parallel CSR range allocation ----------------
__global__ void alloc_kernel(const int* __restrict__ deg_in, int* __restrict__ row_start,
                             int* __restrict__ cursor, int* __restrict__ counter) {
    __shared__ int smem[256];
    __shared__ int base_s;
    int tid = threadIdx.x;
    int i = blockIdx.x * 256 + tid;
    int v = (i < NN) ? deg_in[i] : 0;
    smem[tid] = v;
    __syncthreads();
    for (int off = 1; off < 256; off <<= 1) {
        int t = (tid >= off) ? smem[tid - off] : 0;
        __syncthreads();
        smem[tid] += t;
        __syncthreads();
    }
    int incl = smem[tid];
    if (tid == 0) base_s = atomicAdd(counter, smem[255]);
    __syncthreads();
    if (i < NN) {
        int excl = base_s + incl - v;
        row_start[i] = excl;
        cursor[i]    = excl;
    }
}

// ---------------- scatter edges into CSR ----------------
__global__ void scatter_kernel(const int* __restrict__ src, const int* __restrict__ dst,
                               int* __restrict__ cursor, int* __restrict__ sorted_src) {
    int e = blockIdx.x * blockDim.x + threadIdx.x;
    if (e < NE) {
        int d = dst[e];
        int pos = atomicAdd(&cursor[d], 1);
        sorted_src[pos] = src[e];
    }
}

// ---------------- per-dst gather-aggregate ----------------
// agg[n,s,f] = sum_{e: dst=n} h[src,s,f]*norm_out[src]
// One block per dst node; lane t owns float4 #t of the 2F-float row.
// 8x edge unroll -> 8 row-loads (128B/lane) in flight.
template<int F>
__global__ void aggregate_kernel(const float* __restrict__ h,
                                 const int* __restrict__ row_start,
                                 const int* __restrict__ deg_in,
                                 const int* __restrict__ sorted_src,
                                 const float* __restrict__ norm_out,
                                 float* __restrict__ agg) {
    constexpr int F4 = (2 * F) / 4;     // float4 per row (64 or 123)
    int n = blockIdx.x;
    int t = threadIdx.x;
    if (t >= F4) return;
    int beg = row_start[n];
    int end = beg + deg_in[n];
    const float4* hv = (const float4*)h;
    float4 acc = {0.f, 0.f, 0.f, 0.f};
    int i = beg;
    for (; i + 8 <= end; i += 8) {
        int s[8];
#pragma unroll
        for (int j = 0; j < 8; ++j) s[j] = sorted_src[i + j];
        float nr[8];
#pragma unroll
        for (int j = 0; j < 8; ++j) nr[j] = norm_out[s[j]];
        float4 v[8];
#pragma unroll
        for (int j = 0; j < 8; ++j) v[j] = hv[(size_t)s[j] * F4 + t];
#pragma unroll
        for (int j = 0; j < 8; ++j) {
            acc.x += v[j].x * nr[j];
            acc.y += v[j].y * nr[j];
            acc.z += v[j].z * nr[j];
            acc.w += v[j].w * nr[j];
        }
    }
    for (; i < end; ++i) {
        int s = sorted_src[i];
        float nr = norm_out[s];
        float4 v = hv[(size_t)s * F4 + t];
        acc.x += v.x * nr;
        acc.y += v.y * nr;
        acc.z += v.z * nr;
        acc.w += v.w * nr;
    }
    ((float4*)agg)[(size_t)n * F4 + t] = acc;
}

// ---------------- register-tiled GEMM, BN=256 (all cols in one block) ----------------
// out[m,j] = relu( (A[m,:]*norm_in[m/2]) . W[:,j] + b[j] ), j in [0,246)
// BM=32, BN=256, BK=16, 128 threads, 8x8 thread tile. Grid = 1250 blocks
// (40000/32); A fetched exactly once from memory. Register-prefetch pipeline:
// next tile's global loads issue right after the barrier, consumed next iter.
// FUSE: layer-2 epilogue computes relu -> *fc_w -> mean_s -> reduce -> store
// (each node's full row is in one block, so plain stores, no atomics).
template<int K, bool FUSE>
__global__ __launch_bounds__(128) void gemm_kernel(const float* __restrict__ A,
                                                   const float* __restrict__ W,
                                                   const float* __restrict__ b,
                                                   const float* __restrict__ norm_in,
                                                   float* __restrict__ out,
                                                   const float* __restrict__ fcw,
                                                   const float* __restrict__ fcb) {
    constexpr int BM = 32, BN = 256, BK = 16;
    constexpr int NT = (K + BK - 1) / BK;
    __shared__ float A_s[BK][BM + 4];
    __shared__ float W_s[BK][BN];

    int tid = threadIdx.x;
    int m0  = blockIdx.x * BM;
    int tx  = tid & 31;            // cols 8*tx .. 8*tx+7
    int ty  = tid >> 5;            // rows m0 + 8*ty .. +7

    // A staging geometry: 32 rows x 16 k = 128 float4, 1/thread (transposed store)
    int ar = tid >> 2;             // 0..31
    int ak = (tid & 3) * 4;        // 0,4,8,12
    float anrm = norm_in[(m0 + ar) >> 1];
    const float* aptr = A + (size_t)(m0 + ar) * K;

    float4 va;
    float4 vw[8];

    auto loadA = [&](int kt) {
        int kg = kt + ak;
        if (kg + 3 < K) {
            va = *(const float4*)(aptr + kg);
        } else {
            va.x = (kg + 0 < K) ? aptr[kg + 0] : 0.f;
            va.y = (kg + 1 < K) ? aptr[kg + 1] : 0.f;
            va.z = (kg + 2 < K) ? aptr[kg + 2] : 0.f;
            va.w = (kg + 3 < K) ? aptr[kg + 3] : 0.f;
        }
    };
    auto loadW = [&](int kt) {
#pragma unroll
        for (int it = 0; it < 8; ++it) {
            int f  = it * 128 + tid;
            int k  = f >> 6;
            int c4 = (f & 63) << 2;
            int kg = kt + k;
            float4 w = {0.f, 0.f, 0.f, 0.f};
            if (kg < K) {
                const float* wp = W + (size_t)kg * 246 + c4;
                if (c4 + 3 < 246) {
                    w = *(const float4*)wp;
                } else {
                    if (c4 + 0 < 246) w.x = wp[0];
                    if (c4 + 1 < 246) w.y = wp[1];
                    if (c4 + 2 < 246) w.z = wp[2];
                }
            }
            vw[it] = w;
        }
    };
    auto storeTiles = [&]() {
        A_s[ak + 0][ar] = va.x * anrm;
        A_s[ak + 1][ar] = va.y * anrm;
        A_s[ak + 2][ar] = va.z * anrm;
        A_s[ak + 3][ar] = va.w * anrm;
#pragma unroll
        for (int it = 0; it < 8; ++it) {
            int f = it * 128 + tid;
            *(float4*)&W_s[f >> 6][(f & 63) << 2] = vw[it];
        }
    };

    float acc[8][8];
#pragma unroll
    for (int r = 0; r < 8; ++r)
#pragma unroll
        for (int c = 0; c < 8; ++c) acc[r][c] = 0.f;

    loadA(0);
    loadW(0);
    for (int t0 = 0; t0 < NT; ++t0) {
        storeTiles();
        __syncthreads();
        if (t0 + 1 < NT) {          // prefetch next tile; in flight during compute
            loadA((t0 + 1) * BK);
            loadW((t0 + 1) * BK);
        }
#pragma unroll
        for (int k = 0; k < BK; ++k) {
            float4 a0 = *(const float4*)&A_s[k][8 * ty + 0];
            float4 a1 = *(const float4*)&A_s[k][8 * ty + 4];
            float4 w0 = *(const float4*)&W_s[k][8 * tx + 0];
            float4 w1 = *(const float4*)&W_s[k][8 * tx + 4];
            float av[8] = {a0.x, a0.y, a0.z, a0.w, a1.x, a1.y, a1.z, a1.w};
            float wv[8] = {w0.x, w0.y, w0.z, w0.w, w1.x, w1.y, w1.z, w1.w};
#pragma unroll
            for (int r = 0; r < 8; ++r)
#pragma unroll
                for (int c = 0; c < 8; ++c) acc[r][c] += av[r] * wv[c];
        }
        __syncthreads();
    }

    int c0 = 8 * tx;
    float bj[8];
#pragma unroll
    for (int j = 0; j < 8; ++j) bj[j] = (c0 + j < 246) ? b[c0 + j] : 0.f;

    if (FUSE) {
        float fw[8];
#pragma unroll
        for (int j = 0; j < 8; ++j) fw[j] = (c0 + j < 246) ? fcw[c0 + j] : 0.f;
        float pr[8];
#pragma unroll
        for (int r = 0; r < 8; ++r) {
            float p = 0.f;
#pragma unroll
            for (int j = 0; j < 8; ++j)
                p += fmaxf(acc[r][j] + bj[j], 0.f) * fw[j];
            pr[r] = p;
        }
#pragma unroll
        for (int q = 0; q < 4; ++q) {
            float p = 0.5f * (pr[2 * q] + pr[2 * q + 1]);   // mean over S
#pragma unroll
            for (int off = 16; off > 0; off >>= 1)
                p += __shfl_down(p, off, 32);               // reduce over the 32 tx lanes
            if (tx == 0) {
                int n = (m0 + 8 * ty + 2 * q) >> 1;
                out[n] = p + fcb[0];
            }
        }
    } else {
#pragma unroll
        for (int r = 0; r < 8; ++r) {
            int m = m0 + 8 * ty + r;
            float* op = out + (size_t)m * 246 + c0;
            float v[8];
#pragma unroll
            for (int j = 0; j < 8; ++j) v[j] = fmaxf(acc[r][j] + bj[j], 0.f);
            if (c0 + 7 < 246) {
                float4 v0 = {v[0], v[1], v[2], v[3]};
                float4 v1 = {v[4], v[5], v[6], v[7]};
                *(float4*)(op + 0) = v0;
                *(float4*)(op + 4) = v1;
            } else {
#pragma unroll
                for (int j = 0; j < 8; ++j)
                    if (c0 + j < 246) op[j] = v[j];
            }
        }
    }
}

extern "C" void kernel_launch(void* const* d_in, const int* in_sizes, int n_in,
                              void* d_out, int out_size, void* d_ws, size_t ws_size,
                              hipStream_t stream) {
    const float* feat = (const float*)d_in[0];
    const int*   src  = (const int*)d_in[1];
    const int*   dst  = (const int*)d_in[2];
    const float* W0   = (const float*)d_in[3];
    const float* b0   = (const float*)d_in[4];
    const float* W1   = (const float*)d_in[5];
    const float* b1   = (const float*)d_in[6];
    const float* W2   = (const float*)d_in[7];
    const float* b2   = (const float*)d_in[8];
    const float* fcw  = (const float*)d_in[9];
    const float* fcb  = (const float*)d_in[10];
    float* out = (float*)d_out;

    char* ws = (char*)d_ws;
    size_t off = 0;
    auto alloc = [&](size_t bytes) {
        void* p = ws + off;
        off = (off + bytes + 255) & ~(size_t)255;
        return p;
    };
    int*   deg_out_i = (int*)alloc((2 * NN + 64) * sizeof(int));  // deg_out, deg_in, counter
    int*   deg_in_i  = deg_out_i + NN;
    int*   counter   = deg_out_i + 2 * NN;
    int*   row_start = (int*)alloc(NN * sizeof(int));
    int*   cursor    = (int*)alloc(NN * sizeof(int));
    int*   sorted    = (int*)alloc(NE * sizeof(int));
    float* norm_out  = (float*)alloc(NN * sizeof(float));
    float* norm_in   = (float*)alloc(NN * sizeof(float));
    float* bufA      = (float*)alloc((size_t)NN * SS * FH * sizeof(float));
    float* bufB      = (float*)alloc((size_t)NN * SS * FH * sizeof(float));

    // zero degree counters + alloc counter (ws is poisoned 0xAA before every call)
    hipMemsetAsync(deg_out_i, 0, (2 * NN + 1) * sizeof(int), stream);

    degree_kernel<<<(NE + 255) / 256, 256, 0, stream>>>(src, dst, deg_out_i, deg_in_i);
    norm_kernel<<<(NN + 255) / 256, 256, 0, stream>>>(deg_out_i, deg_in_i, norm_out, norm_in);
    alloc_kernel<<<(NN + 255) / 256, 256, 0, stream>>>(deg_in_i, row_start, cursor, counter);
    scatter_kernel<<<(NE + 255) / 256, 256, 0, stream>>>(src, dst, cursor, sorted);

    const int ggrid = NN * SS / 32;   // 1250 blocks

    // Layer 0: feat [N,S,128] -> agg(bufA) -> gemm -> h1(bufB)
    aggregate_kernel<FIN><<<NN, 64, 0, stream>>>(feat, row_start, deg_in_i, sorted, norm_out, bufA);
    gemm_kernel<FIN, false><<<ggrid, 128, 0, stream>>>(bufA, W0, b0, norm_in, bufB, fcw, fcb);

    // Layer 1
    aggregate_kernel<FH><<<NN, 128, 0, stream>>>(bufB, row_start, deg_in_i, sorted, norm_out, bufA);
    gemm_kernel<FH, false><<<ggrid, 128, 0, stream>>>(bufA, W1, b1, norm_in, bufB, fcw, fcb);

    // Layer 2: gemm fused with relu+mean_s+fc -> out (plain stores, no atomics)
    aggregate_kernel<FH><<<NN, 128, 0, stream>>>(bufB, row_start, deg_in_i, sorted, norm_out, bufA);
    gemm_kernel<FH, true><<<ggrid, 128, 0, stream>>>(bufA, W2, b2, norm_in, out, fcw, fcb);
}

// Round 6
// 567.995 us; speedup vs baseline: 1.3235x; 1.3235x over previous
//
#include <hip/hip_runtime.h>

#define NN 20000      // nodes
#define NE 320000     // edges
#define SS 2          // feature axis
#define FIN 128
#define FH 246

// ---------------- degree histogram ----------------
__global__ void degree_kernel(const int* __restrict__ src, const int* __restrict__ dst,
                              int* __restrict__ deg_out, int* __restrict__ deg_in) {
    int e = blockIdx.x * blockDim.x + threadIdx.x;
    if (e < NE) {
        atomicAdd(&deg_out[src[e]], 1);
        atomicAdd(&deg_in[dst[e]], 1);
    }
}

// ---------------- norms ----------------
__global__ void norm_kernel(const int* __restrict__ deg_out, const int* __restrict__ deg_in,
                            float* __restrict__ norm_out, float* __restrict__ norm_in) {
    int n = blockIdx.x * blockDim.x + threadIdx.x;
    if (n < NN) {
        norm_out[n] = rsqrtf(fmaxf((float)deg_out[n], 1.0f));
        norm_in[n]  = rsqrtf(fmaxf((float)deg_in[n], 1.0f));
    }
}

// ---------------- parallel CSR range allocation ----------------
// Node order in the CSR is irrelevant (ranges just need to be disjoint): per-block
// scan + one atomicAdd for the block base.
__global__ void alloc_kernel(const int* __restrict__ deg_in, int* __restrict__ row_start,
                             int* __restrict__ cursor, int* __restrict__ counter) {
    __shared__ int smem[256];
    __shared__ int base_s;
    int tid = threadIdx.x;
    int i = blockIdx.x * 256 + tid;
    int v = (i < NN) ? deg_in[i] : 0;
    smem[tid] = v;
    __syncthreads();
    for (int off = 1; off < 256; off <<= 1) {
        int t = (tid >= off) ? smem[tid - off] : 0;
        __syncthreads();
        smem[tid] += t;
        __syncthreads();
    }
    int incl = smem[tid];
    if (tid == 0) base_s = atomicAdd(counter, smem[255]);
    __syncthreads();
    if (i < NN) {
        int excl = base_s + incl - v;
        row_start[i] = excl;
        cursor[i]    = excl;
    }
}

// ---------------- scatter edges into CSR ----------------
__global__ void scatter_kernel(const int* __restrict__ src, const int* __restrict__ dst,
                               int* __restrict__ cursor, int* __restrict__ sorted_src) {
    int e = blockIdx.x * blockDim.x + threadIdx.x;
    if (e < NE) {
        int d = dst[e];
        int pos = atomicAdd(&cursor[d], 1);
        sorted_src[pos] = src[e];
    }
}

// ---------------- per-dst gather-aggregate ----------------
// agg[n,s,f] = sum_{e: dst=n} h[src,s,f]*norm_out[src]
// One block per dst node; lane t owns float4 #t of the 2F-float row.
// 8x edge unroll -> 8 row-loads (128B/lane) in flight.
template<int F>
__global__ void aggregate_kernel(const float* __restrict__ h,
                                 const int* __restrict__ row_start,
                                 const int* __restrict__ deg_in,
                                 const int* __restrict__ sorted_src,
                                 const float* __restrict__ norm_out,
                                 float* __restrict__ agg) {
    constexpr int F4 = (2 * F) / 4;     // float4 per row (64 or 123)
    int n = blockIdx.x;
    int t = threadIdx.x;
    if (t >= F4) return;
    int beg = row_start[n];
    int end = beg + deg_in[n];
    const float4* hv = (const float4*)h;
    float4 acc = {0.f, 0.f, 0.f, 0.f};
    int i = beg;
    for (; i + 8 <= end; i += 8) {
        int s[8];
#pragma unroll
        for (int j = 0; j < 8; ++j) s[j] = sorted_src[i + j];
        float nr[8];
#pragma unroll
        for (int j = 0; j < 8; ++j) nr[j] = norm_out[s[j]];
        float4 v[8];
#pragma unroll
        for (int j = 0; j < 8; ++j) v[j] = hv[(size_t)s[j] * F4 + t];
#pragma unroll
        for (int j = 0; j < 8; ++j) {
            acc.x += v[j].x * nr[j];
            acc.y += v[j].y * nr[j];
            acc.z += v[j].z * nr[j];
            acc.w += v[j].w * nr[j];
        }
    }
    for (; i < end; ++i) {
        int s = sorted_src[i];
        float nr = norm_out[s];
        float4 v = hv[(size_t)s * F4 + t];
        acc.x += v.x * nr;
        acc.y += v.y * nr;
        acc.z += v.z * nr;
        acc.w += v.w * nr;
    }
    ((float4*)agg)[(size_t)n * F4 + t] = acc;
}

// ---------------- register-tiled GEMM (round-3 config) ----------------
// out[m,j] = relu( (A[m,:]*norm_in[m/2]) . W[:,j] + b[j] ), j in [0,246)
// BM=64, BN=128, BK=16, 256 threads, thread tile 8x4. Grid (625, 2) = 1250 blocks.
// VGPR ~48 -> high occupancy; this shape measured 92 us (round 3).
// FUSE: layer-2 epilogue computes relu -> *fc_w -> mean_s -> atomicAdd(out[n]).
template<int K, bool FUSE>
__global__ __launch_bounds__(256) void gemm_kernel(const float* __restrict__ A,
                                                   const float* __restrict__ W,
                                                   const float* __restrict__ b,
                                                   const float* __restrict__ norm_in,
                                                   float* __restrict__ out,
                                                   const float* __restrict__ fcw,
                                                   const float* __restrict__ fcb) {
    constexpr int BM = 64, BN = 128, BK = 16;
    __shared__ float A_s[BK][BM + 4];   // transposed; 68-float rows keep 16B alignment
    __shared__ float W_s[BK][BN];

    int tid = threadIdx.x;
    int m0  = blockIdx.x * BM;
    int cb  = blockIdx.y * BN;     // 0 or 128
    int tx  = tid & 31;            // cols cb + 4*tx .. +3
    int ty  = tid >> 5;            // rows m0 + 8*ty .. +7

    float acc[8][4];
#pragma unroll
    for (int r = 0; r < 8; ++r)
#pragma unroll
        for (int c = 0; c < 4; ++c) acc[r][c] = 0.f;

    for (int kt = 0; kt < K; kt += BK) {
        // ---- stage A (64 rows x 16 k), transposed, norm_in fused. 1 float4/thread.
        {
            int r  = tid >> 2;          // 0..63
            int kk = (tid & 3) * 4;     // 0,4,8,12
            int m  = m0 + r;
            int kg = kt + kk;
            float4 v;
            if (kg + 3 < K) {
                v = *(const float4*)(A + (size_t)m * K + kg);
            } else {
                v.x = (kg + 0 < K) ? A[(size_t)m * K + kg + 0] : 0.f;
                v.y = (kg + 1 < K) ? A[(size_t)m * K + kg + 1] : 0.f;
                v.z = (kg + 2 < K) ? A[(size_t)m * K + kg + 2] : 0.f;
                v.w = (kg + 3 < K) ? A[(size_t)m * K + kg + 3] : 0.f;
            }
            float nrm = norm_in[m >> 1];
            A_s[kk + 0][r] = v.x * nrm;
            A_s[kk + 1][r] = v.y * nrm;
            A_s[kk + 2][r] = v.z * nrm;
            A_s[kk + 3][r] = v.w * nrm;
        }
        // ---- stage W (16 k x 128 cols): 2 float4 loads/thread, coalesced
#pragma unroll
        for (int it = 0; it < 2; ++it) {
            int idx = it * 256 + tid;
            int k   = idx >> 5;          // 0..15
            int c4  = (idx & 31) * 4;    // 0..124
            int kg  = kt + k;
            int cc  = cb + c4;
            float4 w;
            if (kg < K) {
                if (cc + 3 < 246) {
                    w = *(const float4*)(W + (size_t)kg * 246 + cc);
                } else {
                    w.x = (cc + 0 < 246) ? W[(size_t)kg * 246 + cc + 0] : 0.f;
                    w.y = (cc + 1 < 246) ? W[(size_t)kg * 246 + cc + 1] : 0.f;
                    w.z = (cc + 2 < 246) ? W[(size_t)kg * 246 + cc + 2] : 0.f;
                    w.w = 0.f;
                }
            } else {
                w.x = w.y = w.z = w.w = 0.f;
            }
            *(float4*)&W_s[k][c4] = w;
        }
        __syncthreads();

#pragma unroll
        for (int k = 0; k < BK; ++k) {
            float4 a0 = *(const float4*)&A_s[k][8 * ty + 0];
            float4 a1 = *(const float4*)&A_s[k][8 * ty + 4];
            float4 w  = *(const float4*)&W_s[k][4 * tx];
            float av[8] = {a0.x, a0.y, a0.z, a0.w, a1.x, a1.y, a1.z, a1.w};
#pragma unroll
            for (int r = 0; r < 8; ++r) {
                acc[r][0] += av[r] * w.x;
                acc[r][1] += av[r] * w.y;
                acc[r][2] += av[r] * w.z;
                acc[r][3] += av[r] * w.w;
            }
        }
        __syncthreads();
    }

    int c0 = cb + 4 * tx;
    float4 bj;
    bj.x = (c0 + 0 < 246) ? b[c0 + 0] : 0.f;
    bj.y = (c0 + 1 < 246) ? b[c0 + 1] : 0.f;
    bj.z = (c0 + 2 < 246) ? b[c0 + 2] : 0.f;
    bj.w = (c0 + 3 < 246) ? b[c0 + 3] : 0.f;

    if (FUSE) {
        // relu -> dot with fc_w (this col-chunk) -> mean over S -> atomicAdd per node
        float4 fw;
        fw.x = (c0 + 0 < 246) ? fcw[c0 + 0] : 0.f;
        fw.y = (c0 + 1 < 246) ? fcw[c0 + 1] : 0.f;
        fw.z = (c0 + 2 < 246) ? fcw[c0 + 2] : 0.f;
        fw.w = (c0 + 3 < 246) ? fcw[c0 + 3] : 0.f;
        float pr[8];
#pragma unroll
        for (int r = 0; r < 8; ++r) {
            float v0 = fmaxf(acc[r][0] + bj.x, 0.f);
            float v1 = fmaxf(acc[r][1] + bj.y, 0.f);
            float v2 = fmaxf(acc[r][2] + bj.z, 0.f);
            float v3 = fmaxf(acc[r][3] + bj.w, 0.f);
            pr[r] = v0 * fw.x + v1 * fw.y + v2 * fw.z + v3 * fw.w;
        }
#pragma unroll
        for (int q = 0; q < 4; ++q) {
            float p = 0.5f * (pr[2 * q] + pr[2 * q + 1]);   // mean over S (rows 8ty+2q, +1)
#pragma unroll
            for (int off = 16; off > 0; off >>= 1)
                p += __shfl_down(p, off, 32);               // reduce over the 32 tx lanes
            if (tx == 0) {
                int n = (m0 + 8 * ty + 2 * q) >> 1;
                if (blockIdx.y == 0) p += fcb[0];           // bias added exactly once
                atomicAdd(&out[n], p);
            }
        }
    } else {
#pragma unroll
        for (int r = 0; r < 8; ++r) {
            int m = m0 + 8 * ty + r;
            float* op = out + (size_t)m * 246 + c0;
            float v0 = fmaxf(acc[r][0] + bj.x, 0.f);
            float v1 = fmaxf(acc[r][1] + bj.y, 0.f);
            float v2 = fmaxf(acc[r][2] + bj.z, 0.f);
            float v3 = fmaxf(acc[r][3] + bj.w, 0.f);
            if (c0 + 3 < 246) {
                float4 v = {v0, v1, v2, v3};
                *(float4*)op = v;
            } else {
                if (c0 + 0 < 246) op[0] = v0;
                if (c0 + 1 < 246) op[1] = v1;
                if (c0 + 2 < 246) op[2] = v2;
            }
        }
    }
}

extern "C" void kernel_launch(void* const* d_in, const int* in_sizes, int n_in,
                              void* d_out, int out_size, void* d_ws, size_t ws_size,
                              hipStream_t stream) {
    const float* feat = (const float*)d_in[0];
    const int*   src  = (const int*)d_in[1];
    const int*   dst  = (const int*)d_in[2];
    const float* W0   = (const float*)d_in[3];
    const float* b0   = (const float*)d_in[4];
    const float* W1   = (const float*)d_in[5];
    const float* b1   = (const float*)d_in[6];
    const float* W2   = (const float*)d_in[7];
    const float* b2   = (const float*)d_in[8];
    const float* fcw  = (const float*)d_in[9];
    const float* fcb  = (const float*)d_in[10];
    float* out = (float*)d_out;

    char* ws = (char*)d_ws;
    size_t off = 0;
    auto alloc = [&](size_t bytes) {
        void* p = ws + off;
        off = (off + bytes + 255) & ~(size_t)255;
        return p;
    };
    int*   deg_out_i = (int*)alloc((2 * NN + 64) * sizeof(int));  // deg_out, deg_in, counter
    int*   deg_in_i  = deg_out_i + NN;
    int*   counter   = deg_out_i + 2 * NN;
    int*   row_start = (int*)alloc(NN * sizeof(int));
    int*   cursor    = (int*)alloc(NN * sizeof(int));
    int*   sorted    = (int*)alloc(NE * sizeof(int));
    float* norm_out  = (float*)alloc(NN * sizeof(float));
    float* norm_in   = (float*)alloc(NN * sizeof(float));
    float* bufA      = (float*)alloc((size_t)NN * SS * FH * sizeof(float));
    float* bufB      = (float*)alloc((size_t)NN * SS * FH * sizeof(float));

    // zero degree counters + alloc counter + fused-output accumulator
    hipMemsetAsync(deg_out_i, 0, (2 * NN + 1) * sizeof(int), stream);
    hipMemsetAsync(out, 0, NN * sizeof(float), stream);

    degree_kernel<<<(NE + 255) / 256, 256, 0, stream>>>(src, dst, deg_out_i, deg_in_i);
    norm_kernel<<<(NN + 255) / 256, 256, 0, stream>>>(deg_out_i, deg_in_i, norm_out, norm_in);
    alloc_kernel<<<(NN + 255) / 256, 256, 0, stream>>>(deg_in_i, row_start, cursor, counter);
    scatter_kernel<<<(NE + 255) / 256, 256, 0, stream>>>(src, dst, cursor, sorted);

    dim3 ggrid(NN * SS / 64, 2);   // 625 x 2 = 1250 blocks

    // Layer 0: feat [N,S,128] -> agg(bufA) -> gemm -> h1(bufB)
    aggregate_kernel<FIN><<<NN, 64, 0, stream>>>(feat, row_start, deg_in_i, sorted, norm_out, bufA);
    gemm_kernel<FIN, false><<<ggrid, 256, 0, stream>>>(bufA, W0, b0, norm_in, bufB, fcw, fcb);

    // Layer 1
    aggregate_kernel<FH><<<NN, 128, 0, stream>>>(bufB, row_start, deg_in_i, sorted, norm_out, bufA);
    gemm_kernel<FH, false><<<ggrid, 256, 0, stream>>>(bufA, W1, b1, norm_in, bufB, fcw, fcb);

    // Layer 2: gemm fused with relu+mean_s+fc -> out (atomicAdd, out pre-zeroed)
    aggregate_kernel<FH><<<NN, 128, 0, stream>>>(bufB, row_start, deg_in_i, sorted, norm_out, bufA);
    gemm_kernel<FH, true><<<ggrid, 256, 0, stream>>>(bufA, W2, b2, norm_in, out, fcw, fcb);
}

// Round 7
// 551.066 us; speedup vs baseline: 1.3642x; 1.0307x over previous
//
#include <hip/hip_runtime.h>

#define NN 20000      // nodes
#define NE 320000     // edges
#define SS 2          // feature axis
#define FIN 128
#define FH 246

// ---------------- degree histogram ----------------
__global__ void degree_kernel(const int* __restrict__ src, const int* __restrict__ dst,
                              int* __restrict__ deg_out, int* __restrict__ deg_in) {
    int e = blockIdx.x * blockDim.x + threadIdx.x;
    if (e < NE) {
        atomicAdd(&deg_out[src[e]], 1);
        atomicAdd(&deg_in[dst[e]], 1);
    }
}

// ---------------- norms ----------------
__global__ void norm_kernel(const int* __restrict__ deg_out, const int* __restrict__ deg_in,
                            float* __restrict__ norm_out, float* __restrict__ norm_in) {
    int n = blockIdx.x * blockDim.x + threadIdx.x;
    if (n < NN) {
        norm_out[n] = rsqrtf(fmaxf((float)deg_out[n], 1.0f));
        norm_in[n]  = rsqrtf(fmaxf((float)deg_in[n], 1.0f));
    }
}

// ---------------- parallel CSR range allocation ----------------
__global__ void alloc_kernel(const int* __restrict__ deg_in, int* __restrict__ row_start,
                             int* __restrict__ cursor, int* __restrict__ counter) {
    __shared__ int smem[256];
    __shared__ int base_s;
    int tid = threadIdx.x;
    int i = blockIdx.x * 256 + tid;
    int v = (i < NN) ? deg_in[i] : 0;
    smem[tid] = v;
    __syncthreads();
    for (int off = 1; off < 256; off <<= 1) {
        int t = (tid >= off) ? smem[tid - off] : 0;
        __syncthreads();
        smem[tid] += t;
        __syncthreads();
    }
    int incl = smem[tid];
    if (tid == 0) base_s = atomicAdd(counter, smem[255]);
    __syncthreads();
    if (i < NN) {
        int excl = base_s + incl - v;
        row_start[i] = excl;
        cursor[i]    = excl;
    }
}

// ---------------- scatter edges into CSR ----------------
__global__ void scatter_kernel(const int* __restrict__ src, const int* __restrict__ dst,
                               int* __restrict__ cursor, int* __restrict__ sorted_src) {
    int e = blockIdx.x * blockDim.x + threadIdx.x;
    if (e < NE) {
        int d = dst[e];
        int pos = atomicAdd(&cursor[d], 1);
        sorted_src[pos] = src[e];
    }
}

// ---------------- chunk-tiled gather-aggregate ----------------
// agg[n, c] = sum_{e: dst=n} h[src, c] * norm_out[src], tiled over 16-float4
// (256 B) column chunks so the concurrent working set (20000 x 256 B = 5.1 MB)
// is ~L2-resident. blockIdx.y = chunk (slow axis -> co-resident blocks share
// the chunk). One wave per block; each 16-lane group owns one dst node; 4x
// edge unroll keeps 16 gathers in flight per wave.
template<int F4TOT>
__global__ void aggregate_tiled(const float* __restrict__ h,
                                const int* __restrict__ row_start,
                                const int* __restrict__ deg_in,
                                const int* __restrict__ sorted_src,
                                const float* __restrict__ norm_out,
                                float* __restrict__ agg) {
    int g  = threadIdx.x >> 4;              // 0..3: node sub-index
    int f4 = threadIdx.x & 15;              // float4 within chunk
    int n  = blockIdx.x * 4 + g;
    int cb = blockIdx.y * 16;               // chunk base (float4 units)
    if (n >= NN) return;
    bool valid = (cb + f4) < F4TOT;
    int idx = valid ? (cb + f4) : (F4TOT - 1);   // clamp; masked at store
    const float4* hv = (const float4*)h;
    int beg = row_start[n];
    int end = beg + deg_in[n];
    float4 acc = {0.f, 0.f, 0.f, 0.f};
    int i = beg;
    for (; i + 4 <= end; i += 4) {
        int s0 = sorted_src[i + 0];
        int s1 = sorted_src[i + 1];
        int s2 = sorted_src[i + 2];
        int s3 = sorted_src[i + 3];
        float n0 = norm_out[s0], n1 = norm_out[s1];
        float n2 = norm_out[s2], n3 = norm_out[s3];
        float4 v0 = hv[(size_t)s0 * F4TOT + idx];
        float4 v1 = hv[(size_t)s1 * F4TOT + idx];
        float4 v2 = hv[(size_t)s2 * F4TOT + idx];
        float4 v3 = hv[(size_t)s3 * F4TOT + idx];
        acc.x += v0.x * n0 + v1.x * n1 + v2.x * n2 + v3.x * n3;
        acc.y += v0.y * n0 + v1.y * n1 + v2.y * n2 + v3.y * n3;
        acc.z += v0.z * n0 + v1.z * n1 + v2.z * n2 + v3.z * n3;
        acc.w += v0.w * n0 + v1.w * n1 + v2.w * n2 + v3.w * n3;
    }
    for (; i < end; ++i) {
        int s = sorted_src[i];
        float nr = norm_out[s];
        float4 v = hv[(size_t)s * F4TOT + idx];
        acc.x += v.x * nr;
        acc.y += v.y * nr;
        acc.z += v.z * nr;
        acc.w += v.w * nr;
    }
    if (valid) ((float4*)agg)[(size_t)n * F4TOT + idx] = acc;
}

// ---------------- register-tiled GEMM (round-3 config) ----------------
// out[m,j] = relu( (A[m,:]*norm_in[m/2]) . W[:,j] + b[j] ), j in [0,246)
// BM=64, BN=128, BK=16, 256 threads, thread tile 8x4. Grid (625, 2) = 1250 blocks.
// VGPR ~48 -> high occupancy; this shape measured 92 us (round 3).
// FUSE: layer-2 epilogue computes relu -> *fc_w -> mean_s -> atomicAdd(out[n]).
template<int K, bool FUSE>
__global__ __launch_bounds__(256) void gemm_kernel(const float* __restrict__ A,
                                                   const float* __restrict__ W,
                                                   const float* __restrict__ b,
                                                   const float* __restrict__ norm_in,
                                                   float* __restrict__ out,
                                                   const float* __restrict__ fcw,
                                                   const float* __restrict__ fcb) {
    constexpr int BM = 64, BN = 128, BK = 16;
    __shared__ float A_s[BK][BM + 4];   // transposed; 68-float rows keep 16B alignment
    __shared__ float W_s[BK][BN];

    int tid = threadIdx.x;
    int m0  = blockIdx.x * BM;
    int cb  = blockIdx.y * BN;     // 0 or 128
    int tx  = tid & 31;            // cols cb + 4*tx .. +3
    int ty  = tid >> 5;            // rows m0 + 8*ty .. +7

    float acc[8][4];
#pragma unroll
    for (int r = 0; r < 8; ++r)
#pragma unroll
        for (int c = 0; c < 4; ++c) acc[r][c] = 0.f;

    for (int kt = 0; kt < K; kt += BK) {
        // ---- stage A (64 rows x 16 k), transposed, norm_in fused. 1 float4/thread.
        {
            int r  = tid >> 2;          // 0..63
            int kk = (tid & 3) * 4;     // 0,4,8,12
            int m  = m0 + r;
            int kg = kt + kk;
            float4 v;
            if (kg + 3 < K) {
                v = *(const float4*)(A + (size_t)m * K + kg);
            } else {
                v.x = (kg + 0 < K) ? A[(size_t)m * K + kg + 0] : 0.f;
                v.y = (kg + 1 < K) ? A[(size_t)m * K + kg + 1] : 0.f;
                v.z = (kg + 2 < K) ? A[(size_t)m * K + kg + 2] : 0.f;
                v.w = (kg + 3 < K) ? A[(size_t)m * K + kg + 3] : 0.f;
            }
            float nrm = norm_in[m >> 1];
            A_s[kk + 0][r] = v.x * nrm;
            A_s[kk + 1][r] = v.y * nrm;
            A_s[kk + 2][r] = v.z * nrm;
            A_s[kk + 3][r] = v.w * nrm;
        }
        // ---- stage W (16 k x 128 cols): 2 float4 loads/thread, coalesced
#pragma unroll
        for (int it = 0; it < 2; ++it) {
            int idx = it * 256 + tid;
            int k   = idx >> 5;          // 0..15
            int c4  = (idx & 31) * 4;    // 0..124
            int kg  = kt + k;
            int cc  = cb + c4;
            float4 w;
            if (kg < K) {
                if (cc + 3 < 246) {
                    w = *(const float4*)(W + (size_t)kg * 246 + cc);
                } else {
                    w.x = (cc + 0 < 246) ? W[(size_t)kg * 246 + cc + 0] : 0.f;
                    w.y = (cc + 1 < 246) ? W[(size_t)kg * 246 + cc + 1] : 0.f;
                    w.z = (cc + 2 < 246) ? W[(size_t)kg * 246 + cc + 2] : 0.f;
                    w.w = 0.f;
                }
            } else {
                w.x = w.y = w.z = w.w = 0.f;
            }
            *(float4*)&W_s[k][c4] = w;
        }
        __syncthreads();

#pragma unroll
        for (int k = 0; k < BK; ++k) {
            float4 a0 = *(const float4*)&A_s[k][8 * ty + 0];
            float4 a1 = *(const float4*)&A_s[k][8 * ty + 4];
            float4 w  = *(const float4*)&W_s[k][4 * tx];
            float av[8] = {a0.x, a0.y, a0.z, a0.w, a1.x, a1.y, a1.z, a1.w};
#pragma unroll
            for (int r = 0; r < 8; ++r) {
                acc[r][0] += av[r] * w.x;
                acc[r][1] += av[r] * w.y;
                acc[r][2] += av[r] * w.z;
                acc[r][3] += av[r] * w.w;
            }
        }
        __syncthreads();
    }

    int c0 = cb + 4 * tx;
    float4 bj;
    bj.x = (c0 + 0 < 246) ? b[c0 + 0] : 0.f;
    bj.y = (c0 + 1 < 246) ? b[c0 + 1] : 0.f;
    bj.z = (c0 + 2 < 246) ? b[c0 + 2] : 0.f;
    bj.w = (c0 + 3 < 246) ? b[c0 + 3] : 0.f;

    if (FUSE) {
        // relu -> dot with fc_w (this col-chunk) -> mean over S -> atomicAdd per node
        float4 fw;
        fw.x = (c0 + 0 < 246) ? fcw[c0 + 0] : 0.f;
        fw.y = (c0 + 1 < 246) ? fcw[c0 + 1] : 0.f;
        fw.z = (c0 + 2 < 246) ? fcw[c0 + 2] : 0.f;
        fw.w = (c0 + 3 < 246) ? fcw[c0 + 3] : 0.f;
        float pr[8];
#pragma unroll
        for (int r = 0; r < 8; ++r) {
            float v0 = fmaxf(acc[r][0] + bj.x, 0.f);
            float v1 = fmaxf(acc[r][1] + bj.y, 0.f);
            float v2 = fmaxf(acc[r][2] + bj.z, 0.f);
            float v3 = fmaxf(acc[r][3] + bj.w, 0.f);
            pr[r] = v0 * fw.x + v1 * fw.y + v2 * fw.z + v3 * fw.w;
        }
#pragma unroll
        for (int q = 0; q < 4; ++q) {
            float p = 0.5f * (pr[2 * q] + pr[2 * q + 1]);   // mean over S (rows 8ty+2q, +1)
#pragma unroll
            for (int off = 16; off > 0; off >>= 1)
                p += __shfl_down(p, off, 32);               // reduce over the 32 tx lanes
            if (tx == 0) {
                int n = (m0 + 8 * ty + 2 * q) >> 1;
                if (blockIdx.y == 0) p += fcb[0];           // bias added exactly once
                atomicAdd(&out[n], p);
            }
        }
    } else {
#pragma unroll
        for (int r = 0; r < 8; ++r) {
            int m = m0 + 8 * ty + r;
            float* op = out + (size_t)m * 246 + c0;
            float v0 = fmaxf(acc[r][0] + bj.x, 0.f);
            float v1 = fmaxf(acc[r][1] + bj.y, 0.f);
            float v2 = fmaxf(acc[r][2] + bj.z, 0.f);
            float v3 = fmaxf(acc[r][3] + bj.w, 0.f);
            if (c0 + 3 < 246) {
                float4 v = {v0, v1, v2, v3};
                *(float4*)op = v;
            } else {
                if (c0 + 0 < 246) op[0] = v0;
                if (c0 + 1 < 246) op[1] = v1;
                if (c0 + 2 < 246) op[2] = v2;
            }
        }
    }
}

extern "C" void kernel_launch(void* const* d_in, const int* in_sizes, int n_in,
                              void* d_out, int out_size, void* d_ws, size_t ws_size,
                              hipStream_t stream) {
    const float* feat = (const float*)d_in[0];
    const int*   src  = (const int*)d_in[1];
    const int*   dst  = (const int*)d_in[2];
    const float* W0   = (const float*)d_in[3];
    const float* b0   = (const float*)d_in[4];
    const float* W1   = (const float*)d_in[5];
    const float* b1   = (const float*)d_in[6];
    const float* W2   = (const float*)d_in[7];
    const float* b2   = (const float*)d_in[8];
    const float* fcw  = (const float*)d_in[9];
    const float* fcb  = (const float*)d_in[10];
    float* out = (float*)d_out;

    char* ws = (char*)d_ws;
    size_t off = 0;
    auto alloc = [&](size_t bytes) {
        void* p = ws + off;
        off = (off + bytes + 255) & ~(size_t)255;
        return p;
    };
    int*   deg_out_i = (int*)alloc((2 * NN + 64) * sizeof(int));  // deg_out, deg_in, counter
    int*   deg_in_i  = deg_out_i + NN;
    int*   counter   = deg_out_i + 2 * NN;
    int*   row_start = (int*)alloc(NN * sizeof(int));
    int*   cursor    = (int*)alloc(NN * sizeof(int));
    int*   sorted    = (int*)alloc(NE * sizeof(int));
    float* norm_out  = (float*)alloc(NN * sizeof(float));
    float* norm_in   = (float*)alloc(NN * sizeof(float));
    float* bufA      = (float*)alloc((size_t)NN * SS * FH * sizeof(float));
    float* bufB      = (float*)alloc((size_t)NN * SS * FH * sizeof(float));

    // zero degree counters + alloc counter + fused-output accumulator
    hipMemsetAsync(deg_out_i, 0, (2 * NN + 1) * sizeof(int), stream);
    hipMemsetAsync(out, 0, NN * sizeof(float), stream);

    degree_kernel<<<(NE + 255) / 256, 256, 0, stream>>>(src, dst, deg_out_i, deg_in_i);
    norm_kernel<<<(NN + 255) / 256, 256, 0, stream>>>(deg_out_i, deg_in_i, norm_out, norm_in);
    alloc_kernel<<<(NN + 255) / 256, 256, 0, stream>>>(deg_in_i, row_start, cursor, counter);
    scatter_kernel<<<(NE + 255) / 256, 256, 0, stream>>>(src, dst, cursor, sorted);

    dim3 ggrid(NN * SS / 64, 2);   // 625 x 2 = 1250 blocks
    const int NB = (NN + 3) / 4;   // 5000 node-groups for the tiled aggregate

    // Layer 0: feat [N,S,128] (64 float4/row, 4 chunks) -> agg(bufA) -> gemm -> h1(bufB)
    aggregate_tiled<64><<<dim3(NB, 4), 64, 0, stream>>>(feat, row_start, deg_in_i, sorted, norm_out, bufA);
    gemm_kernel<FIN, false><<<ggrid, 256, 0, stream>>>(bufA, W0, b0, norm_in, bufB, fcw, fcb);

    // Layer 1: h1 (123 float4/row, 8 chunks)
    aggregate_tiled<123><<<dim3(NB, 8), 64, 0, stream>>>(bufB, row_start, deg_in_i, sorted, norm_out, bufA);
    gemm_kernel<FH, false><<<ggrid, 256, 0, stream>>>(bufA, W1, b1, norm_in, bufB, fcw, fcb);

    // Layer 2: gemm fused with relu+mean_s+fc -> out (atomicAdd, out pre-zeroed)
    aggregate_tiled<123><<<dim3(NB, 8), 64, 0, stream>>>(bufB, row_start, deg_in_i, sorted, norm_out, bufA);
    gemm_kernel<FH, true><<<ggrid, 256, 0, stream>>>(bufA, W2, b2, norm_in, out, fcw, fcb);
}

// Round 9
// 454.369 us; speedup vs baseline: 1.6545x; 1.2128x over previous
//
#include <hip/hip_runtime.h>
#include <hip/hip_fp16.h>

#define NN 20000      // nodes
#define NE 320000     // edges
#define SS 2          // feature axis
#define FIN 128
#define FH 246

typedef _Float16 f16x8 __attribute__((ext_vector_type(8)));
typedef float f32x4 __attribute__((ext_vector_type(4)));

// ---------------- degree histogram ----------------
__global__ void degree_kernel(const int* __restrict__ src, const int* __restrict__ dst,
                              int* __restrict__ deg_out, int* __restrict__ deg_in) {
    int e = blockIdx.x * blockDim.x + threadIdx.x;
    if (e < NE) {
        atomicAdd(&deg_out[src[e]], 1);
        atomicAdd(&deg_in[dst[e]], 1);
    }
}

// ---------------- norms ----------------
__global__ void norm_kernel(const int* __restrict__ deg_out, const int* __restrict__ deg_in,
                            float* __restrict__ norm_out, float* __restrict__ norm_in) {
    int n = blockIdx.x * blockDim.x + threadIdx.x;
    if (n < NN) {
        norm_out[n] = rsqrtf(fmaxf((float)deg_out[n], 1.0f));
        norm_in[n]  = rsqrtf(fmaxf((float)deg_in[n], 1.0f));
    }
}

// ---------------- parallel CSR range allocation ----------------
__global__ void alloc_kernel(const int* __restrict__ deg_in, int* __restrict__ row_start,
                             int* __restrict__ cursor, int* __restrict__ counter) {
    __shared__ int smem[256];
    __shared__ int base_s;
    int tid = threadIdx.x;
    int i = blockIdx.x * 256 + tid;
    int v = (i < NN) ? deg_in[i] : 0;
    smem[tid] = v;
    __syncthreads();
    for (int off = 1; off < 256; off <<= 1) {
        int t = (tid >= off) ? smem[tid - off] : 0;
        __syncthreads();
        smem[tid] += t;
        __syncthreads();
    }
    int incl = smem[tid];
    if (tid == 0) base_s = atomicAdd(counter, smem[255]);
    __syncthreads();
    if (i < NN) {
        int excl = base_s + incl - v;
        row_start[i] = excl;
        cursor[i]    = excl;
    }
}

// ---------------- scatter edges into CSR ----------------
__global__ void scatter_kernel(const int* __restrict__ src, const int* __restrict__ dst,
                               int* __restrict__ cursor, int* __restrict__ sorted_src) {
    int e = blockIdx.x * blockDim.x + threadIdx.x;
    if (e < NE) {
        int d = dst[e];
        int pos = atomicAdd(&cursor[d], 1);
        sorted_src[pos] = src[e];
    }
}

// ---------------- chunk-tiled gather-aggregate (round-7, fp32, known-good) ----------------
template<int F4TOT>
__global__ void aggregate_tiled(const float* __restrict__ h,
                                const int* __restrict__ row_start,
                                const int* __restrict__ deg_in,
                                const int* __restrict__ sorted_src,
                                const float* __restrict__ norm_out,
                                float* __restrict__ agg) {
    int g  = threadIdx.x >> 4;              // 0..3: node sub-index
    int f4 = threadIdx.x & 15;              // float4 within chunk
    int n  = blockIdx.x * 4 + g;
    int cb = blockIdx.y * 16;               // chunk base (float4 units)
    if (n >= NN) return;
    bool valid = (cb + f4) < F4TOT;
    int idx = valid ? (cb + f4) : (F4TOT - 1);
    const float4* hv = (const float4*)h;
    int beg = row_start[n];
    int end = beg + deg_in[n];
    float4 acc = {0.f, 0.f, 0.f, 0.f};
    int i = beg;
    for (; i + 4 <= end; i += 4) {
        int s0 = sorted_src[i + 0];
        int s1 = sorted_src[i + 1];
        int s2 = sorted_src[i + 2];
        int s3 = sorted_src[i + 3];
        float n0 = norm_out[s0], n1 = norm_out[s1];
        float n2 = norm_out[s2], n3 = norm_out[s3];
        float4 v0 = hv[(size_t)s0 * F4TOT + idx];
        float4 v1 = hv[(size_t)s1 * F4TOT + idx];
        float4 v2 = hv[(size_t)s2 * F4TOT + idx];
        float4 v3 = hv[(size_t)s3 * F4TOT + idx];
        acc.x += v0.x * n0 + v1.x * n1 + v2.x * n2 + v3.x * n3;
        acc.y += v0.y * n0 + v1.y * n1 + v2.y * n2 + v3.y * n3;
        acc.z += v0.z * n0 + v1.z * n1 + v2.z * n2 + v3.z * n3;
        acc.w += v0.w * n0 + v1.w * n1 + v2.w * n2 + v3.w * n3;
    }
    for (; i < end; ++i) {
        int s = sorted_src[i];
        float nr = norm_out[s];
        float4 v = hv[(size_t)s * F4TOT + idx];
        acc.x += v.x * nr;
        acc.y += v.y * nr;
        acc.z += v.z * nr;
        acc.w += v.w * nr;
    }
    if (valid) ((float4*)agg)[(size_t)n * F4TOT + idx] = acc;
}

// ---------------- W pre-split: Wt_hi/lo[n][k] = split_f16(W[k][n]), padded 256x256 ----------
__global__ void convert_w_split(const float* __restrict__ W,
                                ushort* __restrict__ Wh, ushort* __restrict__ Wl, int K) {
    int n = blockIdx.x, k = threadIdx.x;
    float v = (k < K && n < 246) ? W[k * 246 + n] : 0.f;
    _Float16 h = (_Float16)v;
    _Float16 l = (_Float16)(v - (float)h);
    Wh[n * 256 + k] = *(ushort*)&h;
    Wl[n * 256 + k] = *(ushort*)&l;
}

__global__ void init_out(float* __restrict__ out, const float* __restrict__ fcb) {
    int i = blockIdx.x * 256 + threadIdx.x;
    if (i < NN) out[i] = fcb[0];
}

// ---------------- split-f16 MFMA GEMM ----------------
// D[m,n] = relu( (A[m,:]*norm_in[m/2]) . W[:,n] + b[n] ), A fp32 [M][K] (K=128|246),
// W pre-split to f16 hi/lo, transposed+padded [256][256]. A split to f16 hi/lo on
// the fly during LDS staging. acc += Ah*Wh + Al*Wh + Ah*Wl (fp32 MFMA accumulate;
// dropped Al*Wl ~ 2^-22 rel). Block 64M x 128N, 4 waves 2x2, wave tile 32x64 via
// 2x4 mfma_f32_16x16x32_f16. Grid (625, 2). Frag layouts round-8-validated.
// FUSE: relu -> *fc_w -> mean_s -> 16-lane reduce -> atomicAdd(out[node]).
template<int K, bool FUSE>
__global__ __launch_bounds__(256) void gemm_split(const float* __restrict__ A,
                                                  const ushort* __restrict__ Wh,
                                                  const ushort* __restrict__ Wl,
                                                  const float* __restrict__ b,
                                                  const float* __restrict__ norm_in,
                                                  void* __restrict__ outv,
                                                  const float* __restrict__ fcw) {
    constexpr int NT = (K + 31) / 32;
    __shared__ __align__(16) _Float16 Ah_s[64][40];
    __shared__ __align__(16) _Float16 Al_s[64][40];
    __shared__ __align__(16) _Float16 Bh_s[128][40];
    __shared__ __align__(16) _Float16 Bl_s[128][40];

    int tid  = threadIdx.x;
    int m0   = blockIdx.x * 64;
    int n0   = blockIdx.y * 128;
    int wave = tid >> 6, lane = tid & 63;
    int wm = wave >> 1, wn = wave & 1;
    int lr = lane & 15, quad = lane >> 4;

    f32x4 acc[2][4];
#pragma unroll
    for (int mi = 0; mi < 2; ++mi)
#pragma unroll
        for (int ni = 0; ni < 4; ++ni) acc[mi][ni] = {0.f, 0.f, 0.f, 0.f};

    int ar = tid >> 2;                 // A row 0..63
    int aq = tid & 3;                  // 8-k chunk within 32-k tile
    float anrm = norm_in[(m0 + ar) >> 1];
    const float* ap = A + (size_t)(m0 + ar) * K;
    const uint4* Whv = (const uint4*)Wh;   // row stride 32 uint4
    const uint4* Wlv = (const uint4*)Wl;

    for (int t0 = 0; t0 < NT; ++t0) {
        int kg0 = t0 * 32 + aq * 8;
        // ---- stage A: load 8 fp32, fuse norm_in, split to f16 hi/lo
        float xv[8];
        if (kg0 + 7 < K) {
            float4 f0 = *(const float4*)(ap + kg0);
            float4 f1 = *(const float4*)(ap + kg0 + 4);
            xv[0] = f0.x; xv[1] = f0.y; xv[2] = f0.z; xv[3] = f0.w;
            xv[4] = f1.x; xv[5] = f1.y; xv[6] = f1.z; xv[7] = f1.w;
        } else {
#pragma unroll
            for (int j = 0; j < 8; ++j) xv[j] = (kg0 + j < K) ? ap[kg0 + j] : 0.f;
        }
        f16x8 vh, vl;
#pragma unroll
        for (int j = 0; j < 8; ++j) {
            float x = xv[j] * anrm;
            _Float16 h = (_Float16)x;
            _Float16 l = (_Float16)(x - (float)h);
            vh[j] = h; vl[j] = l;
        }
        *(f16x8*)&Ah_s[ar][aq * 8] = vh;
        *(f16x8*)&Al_s[ar][aq * 8] = vl;
        // ---- stage B: 128 rows x 32 k, hi+lo (2 uint4/thread each)
#pragma unroll
        for (int it = 0; it < 2; ++it) {
            int f = it * 256 + tid;
            int rn = f >> 2, q = f & 3;
            size_t base = (size_t)(n0 + rn) * 32 + t0 * 4 + q;
            *(uint4*)&Bh_s[rn][q * 8] = Whv[base];
            *(uint4*)&Bl_s[rn][q * 8] = Wlv[base];
        }
        __syncthreads();

        f16x8 ah[2], al[2], bh[4], bl[4];
#pragma unroll
        for (int mi = 0; mi < 2; ++mi) {
            ah[mi] = *(const f16x8*)&Ah_s[wm * 32 + mi * 16 + lr][quad * 8];
            al[mi] = *(const f16x8*)&Al_s[wm * 32 + mi * 16 + lr][quad * 8];
        }
#pragma unroll
        for (int ni = 0; ni < 4; ++ni) {
            bh[ni] = *(const f16x8*)&Bh_s[wn * 64 + ni * 16 + lr][quad * 8];
            bl[ni] = *(const f16x8*)&Bl_s[wn * 64 + ni * 16 + lr][quad * 8];
        }
#pragma unroll
        for (int mi = 0; mi < 2; ++mi)
#pragma unroll
            for (int ni = 0; ni < 4; ++ni) {
                acc[mi][ni] = __builtin_amdgcn_mfma_f32_16x16x32_f16(ah[mi], bh[ni], acc[mi][ni], 0, 0, 0);
                acc[mi][ni] = __builtin_amdgcn_mfma_f32_16x16x32_f16(al[mi], bh[ni], acc[mi][ni], 0, 0, 0);
                acc[mi][ni] = __builtin_amdgcn_mfma_f32_16x16x32_f16(ah[mi], bl[ni], acc[mi][ni], 0, 0, 0);
            }
        __syncthreads();
    }

    if (FUSE) {
        float* out = (float*)outv;
#pragma unroll
        for (int mi = 0; mi < 2; ++mi) {
#pragma unroll
            for (int i = 0; i < 4; ++i) {
                float p = 0.f;
#pragma unroll
                for (int ni = 0; ni < 4; ++ni) {
                    int c = n0 + wn * 64 + ni * 16 + lr;
                    if (c < 246)
                        p += fmaxf(acc[mi][ni][i] + b[c], 0.f) * fcw[c];
                }
#pragma unroll
                for (int off = 8; off > 0; off >>= 1)
                    p += __shfl_down(p, off, 16);
                if (lr == 0) {
                    int m = m0 + wm * 32 + mi * 16 + quad * 4 + i;
                    atomicAdd(&out[m >> 1], 0.5f * p);
                }
            }
        }
    } else {
        float* outF = (float*)outv;    // fp32 [M][246]
#pragma unroll
        for (int ni = 0; ni < 4; ++ni) {
            int c = n0 + wn * 64 + ni * 16 + lr;
            if (c < 246) {
                float bj = b[c];
#pragma unroll
                for (int mi = 0; mi < 2; ++mi)
#pragma unroll
                    for (int i = 0; i < 4; ++i) {
                        int m = m0 + wm * 32 + mi * 16 + quad * 4 + i;
                        outF[(size_t)m * 246 + c] = fmaxf(acc[mi][ni][i] + bj, 0.f);
                    }
            }
        }
    }
}

extern "C" void kernel_launch(void* const* d_in, const int* in_sizes, int n_in,
                              void* d_out, int out_size, void* d_ws, size_t ws_size,
                              hipStream_t stream) {
    const float* feat = (const float*)d_in[0];
    const int*   src  = (const int*)d_in[1];
    const int*   dst  = (const int*)d_in[2];
    const float* W0   = (const float*)d_in[3];
    const float* b0   = (const float*)d_in[4];
    const float* W1   = (const float*)d_in[5];
    const float* b1   = (const float*)d_in[6];
    const float* W2   = (const float*)d_in[7];
    const float* b2   = (const float*)d_in[8];
    const float* fcw  = (const float*)d_in[9];
    const float* fcb  = (const float*)d_in[10];
    float* out = (float*)d_out;

    char* ws = (char*)d_ws;
    size_t off = 0;
    auto alloc = [&](size_t bytes) {
        void* p = ws + off;
        off = (off + bytes + 255) & ~(size_t)255;
        return p;
    };
    int*    deg_out_i = (int*)alloc((2 * NN + 64) * sizeof(int));
    int*    deg_in_i  = deg_out_i + NN;
    int*    counter   = deg_out_i + 2 * NN;
    int*    row_start = (int*)alloc(NN * sizeof(int));
    int*    cursor    = (int*)alloc(NN * sizeof(int));
    int*    sorted    = (int*)alloc(NE * sizeof(int));
    float*  norm_out  = (float*)alloc(NN * sizeof(float));
    float*  norm_in   = (float*)alloc(NN * sizeof(float));
    ushort* Wh0 = (ushort*)alloc(256 * 256 * sizeof(ushort));
    ushort* Wl0 = (ushort*)alloc(256 * 256 * sizeof(ushort));
    ushort* Wh1 = (ushort*)alloc(256 * 256 * sizeof(ushort));
    ushort* Wl1 = (ushort*)alloc(256 * 256 * sizeof(ushort));
    ushort* Wh2 = (ushort*)alloc(256 * 256 * sizeof(ushort));
    ushort* Wl2 = (ushort*)alloc(256 * 256 * sizeof(ushort));
    float*  bufA = (float*)alloc((size_t)NN * SS * FH * sizeof(float));
    float*  bufB = (float*)alloc((size_t)NN * SS * FH * sizeof(float));

    hipMemsetAsync(deg_out_i, 0, (2 * NN + 1) * sizeof(int), stream);

    degree_kernel<<<(NE + 255) / 256, 256, 0, stream>>>(src, dst, deg_out_i, deg_in_i);
    norm_kernel<<<(NN + 255) / 256, 256, 0, stream>>>(deg_out_i, deg_in_i, norm_out, norm_in);
    alloc_kernel<<<(NN + 255) / 256, 256, 0, stream>>>(deg_in_i, row_start, cursor, counter);
    scatter_kernel<<<(NE + 255) / 256, 256, 0, stream>>>(src, dst, cursor, sorted);

    convert_w_split<<<256, 256, 0, stream>>>(W0, Wh0, Wl0, FIN);
    convert_w_split<<<256, 256, 0, stream>>>(W1, Wh1, Wl1, FH);
    convert_w_split<<<256, 256, 0, stream>>>(W2, Wh2, Wl2, FH);
    init_out<<<(NN + 255) / 256, 256, 0, stream>>>(out, fcb);

    const int NB = (NN + 3) / 4;     // 5000
    dim3 ggrid(NN * SS / 64, 2);     // 625 x 2

    // Layer 0: feat (64 float4/node-row) -> agg(bufA, rows of 128) -> gemm -> h1(bufB)
    aggregate_tiled<64><<<dim3(NB, 4), 64, 0, stream>>>(feat, row_start, deg_in_i, sorted, norm_out, bufA);
    gemm_split<FIN, false><<<ggrid, 256, 0, stream>>>(bufA, Wh0, Wl0, b0, norm_in, bufB, fcw);

    // Layer 1: h1 (123 float4/node-row)
    aggregate_tiled<123><<<dim3(NB, 8), 64, 0, stream>>>(bufB, row_start, deg_in_i, sorted, norm_out, bufA);
    gemm_split<FH, false><<<ggrid, 256, 0, stream>>>(bufA, Wh1, Wl1, b1, norm_in, bufB, fcw);

    // Layer 2: fused gemm -> out (atomicAdd; out pre-set to fcb)
    aggregate_tiled<123><<<dim3(NB, 8), 64, 0, stream>>>(bufB, row_start, deg_in_i, sorted, norm_out, bufA);
    gemm_split<FH, true><<<ggrid, 256, 0, stream>>>(bufA, Wh2, Wl2, b2, norm_in, out, fcw);
}